// Round 3
// baseline (1233.479 us; speedup 1.0000x reference)
//
#include <hip/hip_runtime.h>

// MaxUnpooling2D sum-scatter, binning formulation.
//   pool: f32 [16,128,128,64]; ind: int32 same shape (values < 2^22)
//   out:  f32 [16,256,256,64] = 64M floats = 256 MiB
//
// R2 lesson: device-scope fp32 atomicAdd throughput saturates at ~21 G/s
// regardless of occupancy/MLP -> op-count bound. This round converts the
// scatter into: (P1) bin (local_idx,value) pairs by 32KiB output bucket,
// (P2) per-bucket LDS accumulation + single coalesced output write.
// No 256MiB zero pass, no device-scope fp32 atomics in the hot path.

constexpr long long IN_PER_B   = 1LL << 20;           // 2^20 in elems / batch
constexpr long long OUT_PER_B  = 1LL << 22;           // 2^22 out elems / batch
constexpr long long N          = 16 * IN_PER_B;       // 2^24 total in elems
constexpr int LOG2_OUT_PER_B   = 22;
constexpr int LOG2_BUCKET      = 13;                  // 8192 floats = 32 KiB
constexpr int BUCKET_FLOATS    = 1 << LOG2_BUCKET;
constexpr int NBUCKETS         = (int)((16 * OUT_PER_B) >> LOG2_BUCKET); // 8192
constexpr int CAP              = 2304;                // mean 2048, +4sigma ~2230
constexpr int CNT_STRIDE       = 32;                  // u32s; 128 B per counter
constexpr unsigned OVF_MAX     = 65536;

// ws layout (bytes)
constexpr size_t OFF_CNT    = 0;                                   // 1 MiB
constexpr size_t SZ_CNT     = (size_t)NBUCKETS * CNT_STRIDE * 4;
constexpr size_t OFF_OVFCNT = SZ_CNT;                              // 1 KiB pad
constexpr size_t OFF_OVF    = OFF_OVFCNT + 1024;                   // 512 KiB
constexpr size_t OFF_PAIRS  = OFF_OVF + (size_t)OVF_MAX * 8;
constexpr size_t WS_NEEDED  = OFF_PAIRS + (size_t)NBUCKETS * CAP * 8;

// ---------------- binned path ----------------

__global__ void __launch_bounds__(256) phase1_bin(
        const float4* __restrict__ pool4,
        const int4*   __restrict__ ind4,
        unsigned*     __restrict__ cnt,
        unsigned*     __restrict__ ovf_cnt,
        uint2*        __restrict__ ovf,
        uint2*        __restrict__ pairs) {
    const long long i = (long long)blockIdx.x * 256 + threadIdx.x;  // 2^22 thr
    const float4 v  = pool4[i];
    const int4   id = ind4[i];
    const unsigned gbase = (unsigned)(i >> 18) << LOG2_OUT_PER_B;   // batch<<22

    const int   idc[4] = { id.x, id.y, id.z, id.w };
    const float vc[4]  = { v.x, v.y, v.z, v.w };
#pragma unroll
    for (int c = 0; c < 4; ++c) {
        const unsigned g   = gbase + (unsigned)idc[c];
        const unsigned bk  = g >> LOG2_BUCKET;
        const unsigned pos = atomicAdd(&cnt[bk * CNT_STRIDE], 1u);
        if (pos < (unsigned)CAP) {
            pairs[(size_t)bk * CAP + pos] =
                make_uint2(g & (BUCKET_FLOATS - 1), __float_as_uint(vc[c]));
        } else {
            const unsigned op = atomicAdd(ovf_cnt, 1u);
            if (op < OVF_MAX) ovf[op] = make_uint2(g, __float_as_uint(vc[c]));
        }
    }
}

__global__ void __launch_bounds__(256) phase2_acc(
        const unsigned* __restrict__ cnt,
        const uint2*    __restrict__ pairs,
        float4*         __restrict__ out4) {
    __shared__ float lds[BUCKET_FLOATS];                 // 32 KiB
    const int bk = blockIdx.x;
    for (int i = threadIdx.x; i < BUCKET_FLOATS; i += 256) lds[i] = 0.f;
    __syncthreads();

    const unsigned n = min(cnt[bk * CNT_STRIDE], (unsigned)CAP);
    const uint2* p = pairs + (size_t)bk * CAP;
    for (unsigned i = threadIdx.x; i < n; i += 256) {
        const uint2 e = p[i];
        atomicAdd(&lds[e.x], __uint_as_float(e.y));      // ds_add_f32
    }
    __syncthreads();

    float4* dst = out4 + (size_t)bk * (BUCKET_FLOATS / 4);
    const float4* src = (const float4*)lds;
    for (int i = threadIdx.x; i < BUCKET_FLOATS / 4; i += 256) dst[i] = src[i];
}

__global__ void __launch_bounds__(256) phase3_ovf(
        const unsigned* __restrict__ ovf_cnt,
        const uint2*    __restrict__ ovf,
        float*          __restrict__ out) {
    const unsigned n = min(*ovf_cnt, OVF_MAX);
    const unsigned stride = gridDim.x * blockDim.x;
    for (unsigned i = blockIdx.x * blockDim.x + threadIdx.x; i < n; i += stride)
        atomicAdd(&out[ovf[i].x], __uint_as_float(ovf[i].y));
}

// ---------------- fallback path (R2) if ws too small ----------------

__global__ void __launch_bounds__(256) zero_out(float4* __restrict__ out4,
                                               long long n4) {
    const long long stride = (long long)gridDim.x * blockDim.x;
    for (long long i = (long long)blockIdx.x * blockDim.x + threadIdx.x;
         i < n4; i += stride)
        out4[i] = make_float4(0.f, 0.f, 0.f, 0.f);
}

__global__ void __launch_bounds__(256) unpool_scatter(
        const float4* __restrict__ pool4,
        const int4*   __restrict__ ind4,
        float*        __restrict__ out) {
    const long long i = (long long)blockIdx.x * blockDim.x + threadIdx.x;
    const float4 v  = pool4[i];
    const int4   id = ind4[i];
    const long long bofs = (i >> 18) * OUT_PER_B;
    atomicAdd(&out[bofs + (long long)id.x], v.x);
    atomicAdd(&out[bofs + (long long)id.y], v.y);
    atomicAdd(&out[bofs + (long long)id.z], v.z);
    atomicAdd(&out[bofs + (long long)id.w], v.w);
}

extern "C" void kernel_launch(void* const* d_in, const int* in_sizes, int n_in,
                              void* d_out, int out_size, void* d_ws, size_t ws_size,
                              hipStream_t stream) {
    const float* pool = (const float*)d_in[0];
    const int*   ind  = (const int*)d_in[1];
    float*       out  = (float*)d_out;
    const long long n4 = N >> 2;                       // 2^22 vec4s

    if (ws_size >= WS_NEEDED) {
        char* ws = (char*)d_ws;
        unsigned* cnt     = (unsigned*)(ws + OFF_CNT);
        unsigned* ovf_cnt = (unsigned*)(ws + OFF_OVFCNT);
        uint2*    ovf     = (uint2*)   (ws + OFF_OVF);
        uint2*    pairs   = (uint2*)   (ws + OFF_PAIRS);

        // zero bucket counters + overflow counter (ws is poisoned 0xAA)
        hipMemsetAsync(ws, 0, OFF_OVFCNT + 1024, stream);

        phase1_bin<<<(int)(n4 / 256), 256, 0, stream>>>(
            (const float4*)pool, (const int4*)ind, cnt, ovf_cnt, ovf, pairs);
        phase2_acc<<<NBUCKETS, 256, 0, stream>>>(cnt, pairs, (float4*)out);
        phase3_ovf<<<32, 256, 0, stream>>>(ovf_cnt, ovf, out);
    } else {
        // fallback: zero + device-scope atomic scatter (R2 path, ~1.1 ms)
        zero_out<<<4096, 256, 0, stream>>>((float4*)out, (long long)out_size >> 2);
        unpool_scatter<<<(int)(n4 / 256), 256, 0, stream>>>(
            (const float4*)pool, (const int4*)ind, out);
    }
}

// Round 4
// 697.670 us; speedup vs baseline: 1.7680x; 1.7680x over previous
//
#include <hip/hip_runtime.h>

// MaxUnpooling2D sum-scatter via scan-based radix partition (NO global atomics).
//   pool: f32 [16,128,128,64]; ind: int32 same shape, values in [0, 2^22)
//   out:  f32 [16,256,256,64] = 2^26 floats = 256 MiB
//
// R2/R3 lesson: device-visible atomics execute at the coherent point (per-XCD
// L2s non-coherent) and cap at ~20 G ops/s -> any 1-atomic-per-element design
// is ~800 us. This design: LDS histogram -> device scan (exact slot ranges,
// no reservation atomics) -> partition pairs -> per-bucket LDS gather.

constexpr int       LOG2_TILE = 14;                 // 16384 floats = 64 KiB
constexpr int       TILE      = 1 << LOG2_TILE;
constexpr int       NB        = 4096;               // 2^26 / 2^14 buckets
constexpr int       NBLK      = 1024;               // partition blocks
constexpr int       CHUNK     = 16384;              // elems per partition block
constexpr long long N         = 1LL << 24;          // input elements

// ws layout (bytes)
constexpr size_t OFF_COUNTS = 0;                                   // u32[NBLK*NB]
constexpr size_t SZ_COUNTS  = (size_t)NBLK * NB * 4;               // 16 MiB
constexpr size_t OFF_TOTALS = SZ_COUNTS;                           // u32[NB]
constexpr size_t OFF_BASE   = OFF_TOTALS + (size_t)NB * 4;         // u32[NB+1]
constexpr size_t OFF_PAIRS  = OFF_BASE + 32768;                    // uint2[N]
constexpr size_t WS_NEEDED  = OFF_PAIRS + (size_t)N * 8;           // ~144.1 MiB

// ---- A1: per-block LDS histogram over 4096 buckets ----
__global__ void __launch_bounds__(256) a1_count(const int4* __restrict__ ind4,
                                               unsigned* __restrict__ counts) {
    __shared__ unsigned hist[NB];                    // 16 KiB
    for (int b = threadIdx.x; b < NB; b += 256) hist[b] = 0;
    __syncthreads();
    const int blk   = blockIdx.x;
    const unsigned bb = (unsigned)(blk >> 6) << 8;   // batch<<8 (64 blk/batch)
    const long long base4 = (long long)blk * (CHUNK / 4);
    for (int it = 0; it < CHUNK / 4 / 256; ++it) {   // 16 iters
        const int4 id = ind4[base4 + it * 256 + threadIdx.x];
        atomicAdd(&hist[bb | ((unsigned)id.x >> LOG2_TILE)], 1u);
        atomicAdd(&hist[bb | ((unsigned)id.y >> LOG2_TILE)], 1u);
        atomicAdd(&hist[bb | ((unsigned)id.z >> LOG2_TILE)], 1u);
        atomicAdd(&hist[bb | ((unsigned)id.w >> LOG2_TILE)], 1u);
    }
    __syncthreads();
    for (int b = threadIdx.x; b < NB; b += 256)      // coalesced
        counts[(size_t)blk * NB + b] = hist[b];
}

// ---- S1: per-bucket exclusive scan of counts over the 1024 blocks ----
__global__ void __launch_bounds__(256) s1_scan(unsigned* __restrict__ counts,
                                              unsigned* __restrict__ totals) {
    __shared__ unsigned ts[256];
    const int b = blockIdx.x;                        // bucket
    const int t = threadIdx.x;
    unsigned v[4], s = 0;
#pragma unroll
    for (int j = 0; j < 4; ++j) { v[j] = counts[(size_t)(4 * t + j) * NB + b]; s += v[j]; }
    ts[t] = s; __syncthreads();
    for (int off = 1; off < 256; off <<= 1) {        // Hillis-Steele inclusive
        const unsigned x = (t >= off) ? ts[t - off] : 0u;
        __syncthreads();
        ts[t] += x;
        __syncthreads();
    }
    unsigned base = ts[t] - s;                       // exclusive over threads
#pragma unroll
    for (int j = 0; j < 4; ++j) {
        const unsigned c = v[j];
        counts[(size_t)(4 * t + j) * NB + b] = base; // in-place: prefix within bucket
        base += c;
    }
    if (t == 255) totals[b] = ts[255];
}

// ---- S2: scan bucket totals -> bucket_base[NB+1] ----
__global__ void __launch_bounds__(256) s2_scan(const unsigned* __restrict__ totals,
                                              unsigned* __restrict__ bucket_base) {
    __shared__ unsigned ts[256];
    const int t = threadIdx.x;
    unsigned v[16], s = 0;
#pragma unroll
    for (int j = 0; j < 16; ++j) { v[j] = totals[t * 16 + j]; s += v[j]; }
    ts[t] = s; __syncthreads();
    for (int off = 1; off < 256; off <<= 1) {
        const unsigned x = (t >= off) ? ts[t - off] : 0u;
        __syncthreads();
        ts[t] += x;
        __syncthreads();
    }
    unsigned base = ts[t] - s;
#pragma unroll
    for (int j = 0; j < 16; ++j) { bucket_base[t * 16 + j] = base; base += v[j]; }
    if (t == 255) bucket_base[NB] = ts[255];
}

// ---- A2: partition (local_idx, value) pairs into exact slot ranges ----
__global__ void __launch_bounds__(256) a2_scatter(
        const float4*   __restrict__ pool4,
        const int4*     __restrict__ ind4,
        const unsigned* __restrict__ counts,
        const unsigned* __restrict__ bucket_base,
        uint2*          __restrict__ pairs) {
    __shared__ unsigned cur[NB];                     // 16 KiB global cursors
    const int blk = blockIdx.x;
    for (int b = threadIdx.x; b < NB; b += 256)      // coalesced init
        cur[b] = bucket_base[b] + counts[(size_t)blk * NB + b];
    __syncthreads();
    const unsigned bb = (unsigned)(blk >> 6) << 8;
    const long long base4 = (long long)blk * (CHUNK / 4);
    for (int it = 0; it < CHUNK / 4 / 256; ++it) {
        const long long i4 = base4 + it * 256 + threadIdx.x;
        const int4   id = ind4[i4];
        const float4 v  = pool4[i4];
        unsigned b0 = bb | ((unsigned)id.x >> LOG2_TILE);
        unsigned p0 = atomicAdd(&cur[b0], 1u);       // LDS returning atomic
        pairs[p0] = make_uint2((unsigned)id.x & (TILE - 1), __float_as_uint(v.x));
        unsigned b1 = bb | ((unsigned)id.y >> LOG2_TILE);
        unsigned p1 = atomicAdd(&cur[b1], 1u);
        pairs[p1] = make_uint2((unsigned)id.y & (TILE - 1), __float_as_uint(v.y));
        unsigned b2 = bb | ((unsigned)id.z >> LOG2_TILE);
        unsigned p2 = atomicAdd(&cur[b2], 1u);
        pairs[p2] = make_uint2((unsigned)id.z & (TILE - 1), __float_as_uint(v.z));
        unsigned b3 = bb | ((unsigned)id.w >> LOG2_TILE);
        unsigned p3 = atomicAdd(&cur[b3], 1u);
        pairs[p3] = make_uint2((unsigned)id.w & (TILE - 1), __float_as_uint(v.w));
    }
}

// ---- C: per-bucket LDS gather + single coalesced output write ----
__global__ void __launch_bounds__(256) c_accum(
        const unsigned* __restrict__ bucket_base,
        const uint2*    __restrict__ pairs,
        float4*         __restrict__ out4) {
    __shared__ float tile[TILE];                     // 64 KiB
    const int bk = blockIdx.x;
    for (int i = threadIdx.x; i < TILE; i += 256) tile[i] = 0.f;
    __syncthreads();
    const unsigned s = bucket_base[bk], e = bucket_base[bk + 1];
    for (unsigned i = s + threadIdx.x; i < e; i += 256) {
        const uint2 p = pairs[i];
        atomicAdd(&tile[p.x], __uint_as_float(p.y)); // ds_add_f32 (CU-local)
    }
    __syncthreads();
    const float4* src = (const float4*)tile;
    float4* dst = out4 + (size_t)bk * (TILE / 4);
    for (int i = threadIdx.x; i < TILE / 4; i += 256) dst[i] = src[i];
}

// ---------------- fallback (R2 path) if ws too small ----------------
__global__ void __launch_bounds__(256) zero_out(float4* __restrict__ out4,
                                               long long n4) {
    const long long stride = (long long)gridDim.x * blockDim.x;
    for (long long i = (long long)blockIdx.x * blockDim.x + threadIdx.x;
         i < n4; i += stride)
        out4[i] = make_float4(0.f, 0.f, 0.f, 0.f);
}

__global__ void __launch_bounds__(256) unpool_scatter(
        const float4* __restrict__ pool4,
        const int4*   __restrict__ ind4,
        float*        __restrict__ out) {
    const long long i = (long long)blockIdx.x * blockDim.x + threadIdx.x;
    const float4 v  = pool4[i];
    const int4   id = ind4[i];
    const long long bofs = (i >> 18) << 22;
    atomicAdd(&out[bofs + (long long)id.x], v.x);
    atomicAdd(&out[bofs + (long long)id.y], v.y);
    atomicAdd(&out[bofs + (long long)id.z], v.z);
    atomicAdd(&out[bofs + (long long)id.w], v.w);
}

extern "C" void kernel_launch(void* const* d_in, const int* in_sizes, int n_in,
                              void* d_out, int out_size, void* d_ws, size_t ws_size,
                              hipStream_t stream) {
    const float* pool = (const float*)d_in[0];
    const int*   ind  = (const int*)d_in[1];
    float*       out  = (float*)d_out;

    if (ws_size >= WS_NEEDED) {
        char* ws = (char*)d_ws;
        unsigned* counts      = (unsigned*)(ws + OFF_COUNTS);
        unsigned* totals      = (unsigned*)(ws + OFF_TOTALS);
        unsigned* bucket_base = (unsigned*)(ws + OFF_BASE);
        uint2*    pairs       = (uint2*)   (ws + OFF_PAIRS);
        // counts/totals/base/pairs are all fully overwritten each call:
        // no memset needed despite 0xAA ws re-poison.
        a1_count  <<<NBLK, 256, 0, stream>>>((const int4*)ind, counts);
        s1_scan   <<<NB,   256, 0, stream>>>(counts, totals);
        s2_scan   <<<1,    256, 0, stream>>>(totals, bucket_base);
        a2_scatter<<<NBLK, 256, 0, stream>>>((const float4*)pool, (const int4*)ind,
                                             counts, bucket_base, pairs);
        c_accum   <<<NB,   256, 0, stream>>>(bucket_base, pairs, (float4*)out);
    } else {
        // fallback: zero + device-scope atomic scatter (~1.1 ms)
        zero_out<<<4096, 256, 0, stream>>>((float4*)out, (long long)out_size >> 2);
        unpool_scatter<<<(int)(N >> 2) / 256, 256, 0, stream>>>(
            (const float4*)pool, (const int4*)ind, out);
    }
}

// Round 6
// 632.307 us; speedup vs baseline: 1.9508x; 1.1034x over previous
//
#include <hip/hip_runtime.h>

// MaxUnpooling2D sum-scatter, fused partition + capacity-padded segments.
//   pool: f32 [16,128,128,64]; ind: int32 same shape, values in [0, 2^22)
//   out:  f32 [16,256,256,64] = 2^26 floats = 256 MiB
//
// R4 lessons: (a) scatter via pairs works (177us vs 805us atomic), but 8B
// interleaved stores gave 2.5x HBM write-amp; (b) ~520us hidden in a1/s1/c +
// fixed harness restore overhead. This round: ONE partition kernel
// (LDS hist -> 512 bulk device-atomic reservations/block -> run-of-16
// pair writes into capacity-padded segments) + 32KiB-tile accumulate.
// Device atomics: 1M total (16x fewer than R3's per-elem reservation).
// (R5 was an infra failure — same source resubmitted.)

constexpr long long N        = 1LL << 24;     // input elements
constexpr int LOG2_TILE      = 13;            // 8192 floats = 32 KiB out tile
constexpr int TILE           = 1 << LOG2_TILE;
constexpr int NB             = 8192;          // total tiles (16 batches x 512)
constexpr int TPB            = 512;           // tiles per batch
constexpr int CAP            = 2304;          // mean 2048, +4sigma ~2230
constexpr int CHUNK          = 8192;          // elems per partition block
constexpr int NBLK           = (int)(N / CHUNK);   // 2048 (128 per batch)
constexpr unsigned OVF_MAX   = 65536;

// ws layout (bytes)
constexpr size_t OFF_CUR    = 0;                                  // u32[NB]
constexpr size_t OFF_OVFCNT = (size_t)NB * 4;                     // 32 KiB
constexpr size_t OFF_OVF    = OFF_OVFCNT + 4096;                  // pad
constexpr size_t OFF_PAIRS  = OFF_OVF + (size_t)OVF_MAX * 8;      // 512 KiB
constexpr size_t WS_NEEDED  = OFF_PAIRS + (size_t)NB * CAP * 8;   // ~144.5 MiB

// ---- P1: fused count + bulk-reserve + partition ----
__global__ void __launch_bounds__(256) p1_partition(
        const float4* __restrict__ pool4,
        const int4*   __restrict__ ind4,
        unsigned*     __restrict__ cur_g,     // [NB] global segment cursors
        unsigned*     __restrict__ ovf_cnt,
        uint2*        __restrict__ ovf,
        uint2*        __restrict__ pairs) {
    __shared__ unsigned hist[TPB];            // per-in-batch-tile counts
    __shared__ unsigned base[TPB];            // reserved global segment base
    __shared__ unsigned cur2[TPB];            // within-block position cursors
    const int t   = threadIdx.x;
    const int blk = blockIdx.x;
    for (int b = t; b < TPB; b += 256) { hist[b] = 0u; cur2[b] = 0u; }
    __syncthreads();

    const long long base4 = (long long)blk * (CHUNK / 4);
    int4 id[8];
#pragma unroll
    for (int i = 0; i < 8; ++i) id[i] = ind4[base4 + i * 256 + t];
#pragma unroll
    for (int i = 0; i < 8; ++i) {
        atomicAdd(&hist[(unsigned)id[i].x >> LOG2_TILE], 1u);  // ds_add, no ret
        atomicAdd(&hist[(unsigned)id[i].y >> LOG2_TILE], 1u);
        atomicAdd(&hist[(unsigned)id[i].z >> LOG2_TILE], 1u);
        atomicAdd(&hist[(unsigned)id[i].w >> LOG2_TILE], 1u);
    }
    __syncthreads();

    const unsigned bb = (unsigned)(blk >> 7) * TPB;   // batch * 512
    for (int b = t; b < TPB; b += 256)                // 512 device atomics/block
        base[b] = atomicAdd(&cur_g[bb + b], hist[b]);
    __syncthreads();

#pragma unroll
    for (int i = 0; i < 8; ++i) {
        const float4 v = pool4[base4 + i * 256 + t];
        const int  ic[4] = { id[i].x, id[i].y, id[i].z, id[i].w };
        const float vc[4] = { v.x, v.y, v.z, v.w };
#pragma unroll
        for (int c = 0; c < 4; ++c) {
            const unsigned lb  = (unsigned)ic[c] >> LOG2_TILE;   // in-batch tile
            const unsigned loc = (unsigned)ic[c] & (TILE - 1);
            const unsigned pos = atomicAdd(&cur2[lb], 1u) + base[lb];
            const unsigned gb  = bb + lb;                        // global tile
            if (pos < (unsigned)CAP) {
                pairs[(size_t)gb * CAP + pos] =
                    make_uint2(loc, __float_as_uint(vc[c]));
            } else {                                             // ~never
                const unsigned op = atomicAdd(ovf_cnt, 1u);
                if (op < OVF_MAX)
                    ovf[op] = make_uint2((gb << LOG2_TILE) | loc,
                                         __float_as_uint(vc[c]));
            }
        }
    }
}

// ---- C2: per-tile LDS accumulate + single coalesced output write ----
__global__ void __launch_bounds__(256) c2_accum(
        const unsigned* __restrict__ cur_g,
        const uint2*    __restrict__ pairs,
        float4*         __restrict__ out4) {
    __shared__ float tile[TILE];                      // 32 KiB -> 5 blocks/CU
    const int bk = blockIdx.x;
    for (int i = threadIdx.x; i < TILE; i += 256) tile[i] = 0.f;
    __syncthreads();
    const unsigned n = min(cur_g[bk], (unsigned)CAP);
    const uint2* p = pairs + (size_t)bk * CAP;
    for (unsigned i = threadIdx.x; i < n; i += 256) {
        const uint2 e = p[i];
        atomicAdd(&tile[e.x], __uint_as_float(e.y));  // ds_add_f32, CU-local
    }
    __syncthreads();
    const float4* src = (const float4*)tile;
    float4* dst = out4 + (size_t)bk * (TILE / 4);
    for (int i = threadIdx.x; i < TILE / 4; i += 256) dst[i] = src[i];
}

// ---- D3: drain overflow list (0 entries in practice) ----
__global__ void __launch_bounds__(256) d3_drain(
        const unsigned* __restrict__ ovf_cnt,
        const uint2*    __restrict__ ovf,
        float*          __restrict__ out) {
    const unsigned n = min(*ovf_cnt, OVF_MAX);
    const unsigned stride = gridDim.x * blockDim.x;
    for (unsigned i = blockIdx.x * blockDim.x + threadIdx.x; i < n; i += stride)
        atomicAdd(&out[ovf[i].x], __uint_as_float(ovf[i].y));
}

// ---------------- fallback (R2 path) if ws too small ----------------
__global__ void __launch_bounds__(256) zero_out(float4* __restrict__ out4,
                                               long long n4) {
    const long long stride = (long long)gridDim.x * blockDim.x;
    for (long long i = (long long)blockIdx.x * blockDim.x + threadIdx.x;
         i < n4; i += stride)
        out4[i] = make_float4(0.f, 0.f, 0.f, 0.f);
}

__global__ void __launch_bounds__(256) unpool_scatter(
        const float4* __restrict__ pool4,
        const int4*   __restrict__ ind4,
        float*        __restrict__ out) {
    const long long i = (long long)blockIdx.x * blockDim.x + threadIdx.x;
    const float4 v  = pool4[i];
    const int4   id = ind4[i];
    const long long bofs = (i >> 18) << 22;
    atomicAdd(&out[bofs + (long long)id.x], v.x);
    atomicAdd(&out[bofs + (long long)id.y], v.y);
    atomicAdd(&out[bofs + (long long)id.z], v.z);
    atomicAdd(&out[bofs + (long long)id.w], v.w);
}

extern "C" void kernel_launch(void* const* d_in, const int* in_sizes, int n_in,
                              void* d_out, int out_size, void* d_ws, size_t ws_size,
                              hipStream_t stream) {
    const float* pool = (const float*)d_in[0];
    const int*   ind  = (const int*)d_in[1];
    float*       out  = (float*)d_out;

    if (ws_size >= WS_NEEDED) {
        char* ws = (char*)d_ws;
        unsigned* cur_g   = (unsigned*)(ws + OFF_CUR);
        unsigned* ovf_cnt = (unsigned*)(ws + OFF_OVFCNT);
        uint2*    ovf     = (uint2*)   (ws + OFF_OVF);
        uint2*    pairs   = (uint2*)   (ws + OFF_PAIRS);

        // zero cursors + overflow counter (ws re-poisoned 0xAA every call)
        hipMemsetAsync(ws, 0, OFF_OVF, stream);

        p1_partition<<<NBLK, 256, 0, stream>>>(
            (const float4*)pool, (const int4*)ind, cur_g, ovf_cnt, ovf, pairs);
        c2_accum<<<NB, 256, 0, stream>>>(cur_g, pairs, (float4*)out);
        d3_drain<<<16, 256, 0, stream>>>(ovf_cnt, ovf, out);
    } else {
        // fallback: zero + device-scope atomic scatter (~1.1 ms)
        zero_out<<<4096, 256, 0, stream>>>((float4*)out, (long long)out_size >> 2);
        unpool_scatter<<<(int)(N >> 2) / 256, 256, 0, stream>>>(
            (const float4*)pool, (const int4*)ind, out);
    }
}